// Round 6
// baseline (140.203 us; speedup 1.0000x reference)
//
#include <hip/hip_runtime.h>
#include <math.h>

typedef __attribute__((ext_vector_type(8))) __bf16 bf16x8;
typedef __attribute__((ext_vector_type(4))) __bf16 bf16x4v;
typedef __attribute__((ext_vector_type(16))) float f32x16;

#define N_TOK  4096
#define C_DIM  1024
#define N_EXP  8
#define CAP    4096

// workspace layout (bytes). ws_size ~= 256 MiB (poison-fill WRITE_SIZE evidence).
// NOTE round-3 postmortem: '<<' binds looser than '+' — keep offsets parenthesized.
#define WS_CNT    0                                   // 32 B
#define WS_PERM   32768                               // 128 KB: per-expert slot lists
#define WS_XB     ((size_t)1 << 20)                   // 8 MB: x in bf16
#define WS_WT     (WS_XB + ((size_t)8 << 20))         // 16 MB: W^T bf16

// async global->LDS, 16B per lane. LDS dest is wave-uniform base + lane*16.
#define GLD16(g, l)                                                        \
  __builtin_amdgcn_global_load_lds(                                        \
      (const __attribute__((address_space(1))) void*)(g),                  \
      (__attribute__((address_space(3))) void*)(l), 16, 0, 0)

// ---------------------------------------------------------------------------
// prep: fused router (blocks 0..255) + W transpose/bf16 (blocks 256..8447).
// Router blocks also build the per-expert slot lists directly (LDS-aggregated
// counts -> 8 spread global atomics per block; cnt pre-zeroed by a 32 B
// memset, NOT by block 0 — that would race with other blocks' atomics).
// ---------------------------------------------------------------------------
__global__ __launch_bounds__(256)
void prep_kernel(const float* __restrict__ x, const float* __restrict__ wg,
                 const float* __restrict__ bias, const float* __restrict__ W,
                 __bf16* __restrict__ xb, float* __restrict__ probs,
                 __bf16* __restrict__ Wt, int* __restrict__ cnt,
                 int* __restrict__ perm) {
  __shared__ __align__(16) char smem[32768];
  __shared__ int lcnt[N_EXP], base[N_EXP];
  const int tid = threadIdx.x;

  if (blockIdx.x < 256) {
    // ---------------- router ----------------
    float (*wgT)[C_DIM] = (float (*)[C_DIM])smem;   // [N_EXP][C_DIM], 32 KB
    if (tid < N_EXP) lcnt[tid] = 0;

#pragma unroll
    for (int i = 0; i < 8; ++i) {
      const float4 v = ((const float4*)wg)[i * 256 + tid];
      const int f = (i * 256 + tid) * 4;
      const int c = f >> 3;
      const int e = f & 7;
      wgT[e][c] = v.x; wgT[e + 1][c] = v.y; wgT[e + 2][c] = v.z; wgT[e + 3][c] = v.w;
    }
    __syncthreads();

    const int lane = tid & 63;
    const int wv   = tid >> 6;
    int re0[4], re1[4], rs0[4], rs1[4];   // lane0-valid per s

#pragma unroll
    for (int s = 0; s < 4; ++s) {
      const int t = blockIdx.x * 16 + wv * 4 + s;
      const float4* xrow = (const float4*)(x + (size_t)t * C_DIM);
      float acc[N_EXP];
#pragma unroll
      for (int e = 0; e < N_EXP; ++e) acc[e] = 0.f;

#pragma unroll
      for (int j = 0; j < 4; ++j) {
        const int c4 = j * 64 + lane;
        const float4 v = xrow[c4];
        bf16x4v bv = { (__bf16)v.x, (__bf16)v.y, (__bf16)v.z, (__bf16)v.w };
        *(bf16x4v*)(xb + (size_t)t * C_DIM + c4 * 4) = bv;
#pragma unroll
        for (int e = 0; e < N_EXP; ++e) {
          const float4 w = *(const float4*)&wgT[e][c4 * 4];
          acc[e] += v.x * w.x + v.y * w.y + v.z * w.z + v.w * w.w;
        }
      }

#pragma unroll
      for (int off = 32; off >= 1; off >>= 1) {
#pragma unroll
        for (int e = 0; e < N_EXP; ++e) acc[e] += __shfl_xor(acc[e], off, 64);
      }

      if (lane == 0) {
        float l[N_EXP];
#pragma unroll
        for (int e = 0; e < N_EXP; ++e) l[e] = acc[e] + bias[e];
        int e0 = 0;
#pragma unroll
        for (int e = 1; e < N_EXP; ++e) if (l[e] > l[e0]) e0 = e;
        int e1 = (e0 == 0) ? 1 : 0;
#pragma unroll
        for (int e = 0; e < N_EXP; ++e) if (e != e0 && l[e] > l[e1]) e1 = e;
        const float p0 = 1.f / (1.f + expf(l[e1] - l[e0]));
        probs[t * 2]     = p0;
        probs[t * 2 + 1] = 1.f - p0;
        re0[s] = e0; re1[s] = e1;
        rs0[s] = atomicAdd(&lcnt[e0], 1);
        rs1[s] = atomicAdd(&lcnt[e1], 1);
      }
    }
    __syncthreads();
    if (tid < N_EXP) base[tid] = atomicAdd(&cnt[tid], lcnt[tid]);
    __syncthreads();
    if (lane == 0) {
#pragma unroll
      for (int s = 0; s < 4; ++s) {
        const int t = blockIdx.x * 16 + wv * 4 + s;
        perm[re0[s] * CAP + base[re0[s]] + rs0[s]] = t * 2;
        perm[re1[s] * CAP + base[re1[s]] + rs1[s]] = t * 2 + 1;
      }
    }
  } else {
    // ---------------- W transpose + bf16 convert ----------------
    __bf16 (*tile)[33] = (__bf16 (*)[33])smem;      // [32][33]
    const int b  = blockIdx.x - 256;
    const int e  = b >> 10;
    const int r  = b & 1023;
    const int i0 = (r >> 5) * 32;
    const int o0 = (r & 31) * 32;
    const float* We  = W  + (size_t)e * C_DIM * C_DIM;
    __bf16*      Wte = Wt + (size_t)e * C_DIM * C_DIM;
    const int tx = tid & 31, ty = tid >> 5;
#pragma unroll
    for (int j = 0; j < 32; j += 8)
      tile[ty + j][tx] = (__bf16)We[(size_t)(i0 + ty + j) * C_DIM + o0 + tx];
    __syncthreads();
#pragma unroll
    for (int j = 0; j < 32; j += 8)
      Wte[(size_t)(o0 + ty + j) * C_DIM + i0 + tx] = tile[tx][ty + j];
  }
}

// ---------------------------------------------------------------------------
// Grouped GEMM: 128x128 tile, BK=64, 4 waves x (2x2 of 32x32x16 bf16 MFMA —
// m119: ~20% better FLOP/cyc than 16x16x32). global_load_lds staging with
// XOR chunk swizzle (row r's 8x16B chunks permuted by r&7) -> conflict-free
// b128 fragment reads. Epilogue: plain bf16 stores into the slot buffer
// packed in d_out's y region: token t's 4 KiB = [buf0[t] | buf1[t]].
// A/B operand layout: m(or n)=lane&31, k=(lane>>5)*8+j. C/D (m74/m101):
// col=lane&31, row=(reg&3)+8*(reg>>2)+4*(lane>>5).
// ---------------------------------------------------------------------------
__global__ __launch_bounds__(256)
void moe_gemm(const __bf16* __restrict__ xb, const __bf16* __restrict__ Wt,
              const int* __restrict__ cnt, const int* __restrict__ perm,
              __bf16* __restrict__ buf) {
  const int e  = blockIdx.z;
  const int n0 = blockIdx.x * 128;
  const int m0 = blockIdx.y * 128;
  const int count = cnt[e];
  if (m0 >= count) return;

  const int*    permE = perm + e * CAP;
  const __bf16* We    = Wt + (size_t)e * C_DIM * C_DIM;

  __shared__ char AsB[16384];   // 128 rows x 128 B (64 bf16), chunk-swizzled
  __shared__ char BsB[16384];
  __bf16* As = (__bf16*)AsB;
  __bf16* Bs = (__bf16*)BsB;

  const int tid  = threadIdx.x;
  const int lane = tid & 63;
  const int wv   = tid >> 6;
  const int wr = wv >> 1, wc = wv & 1;
  const int mw = wr * 64, nw = wc * 64;
  const int l32 = lane & 31, hi = lane >> 5;

  const int rsub  = lane >> 3;          // 0..7
  const int chunk = (lane & 7) ^ rsub;  // XOR swizzle key = row&7
  int tk[4];
#pragma unroll
  for (int q = 0; q < 4; ++q) {
    const int i = m0 + wv * 32 + q * 8 + rsub;
    tk[q] = (i < count) ? (permE[i] >> 1) : 0;
  }
  const char* gB = (const char*)We + (size_t)(n0 + wv * 32 + rsub) * 2048 + chunk * 16;
  char* ldsA = AsB + wv * 4096;     // + q*1024; lane*16 appended by HW
  char* ldsB = BsB + wv * 4096;

  f32x16 acc[2][2];
#pragma unroll
  for (int mg = 0; mg < 2; ++mg)
#pragma unroll
    for (int ng = 0; ng < 2; ++ng)
#pragma unroll
      for (int r = 0; r < 16; ++r) acc[mg][ng][r] = 0.f;

  for (int kt = 0; kt < 16; ++kt) {
    const int kb = kt * 128;   // byte offset along K (64 bf16)
#pragma unroll
    for (int q = 0; q < 4; ++q)
      GLD16((const char*)xb + (size_t)tk[q] * 2048 + kb + chunk * 16,
            ldsA + q * 1024);
#pragma unroll
    for (int q = 0; q < 4; ++q)
      GLD16(gB + (size_t)q * 8 * 2048 + kb, ldsB + q * 1024);
    __syncthreads();

#pragma unroll
    for (int ks = 0; ks < 4; ++ks) {
      const int c = ks * 2 + hi;        // 16B chunk index along the 128B row
      bf16x8 afr[2], bfr[2];
#pragma unroll
      for (int mg = 0; mg < 2; ++mg) {
        const int rA = mw + mg * 32 + l32;
        afr[mg] = *(const bf16x8*)(As + rA * 64 + ((c ^ (rA & 7)) << 3));
      }
#pragma unroll
      for (int ng = 0; ng < 2; ++ng) {
        const int rB = nw + ng * 32 + l32;
        bfr[ng] = *(const bf16x8*)(Bs + rB * 64 + ((c ^ (rB & 7)) << 3));
      }
#pragma unroll
      for (int mg = 0; mg < 2; ++mg)
#pragma unroll
        for (int ng = 0; ng < 2; ++ng)
          acc[mg][ng] = __builtin_amdgcn_mfma_f32_32x32x16_bf16(
              afr[mg], bfr[ng], acc[mg][ng], 0, 0, 0);
    }
    __syncthreads();
  }

  // epilogue: C/D row=(reg&3)+8*(reg>>2)+4*hi, col=l32
#pragma unroll
  for (int mg = 0; mg < 2; ++mg) {
#pragma unroll
    for (int r = 0; r < 16; ++r) {
      const int row = (r & 3) + 8 * (r >> 2) + 4 * hi;
      const int i = m0 + mw + mg * 32 + row;
      if (i < count) {
        const int pe = permE[i];
        __bf16* orow = buf + (size_t)(pe >> 1) * 2048 + (pe & 1) * 1024 +
                       n0 + nw + l32;
#pragma unroll
        for (int ng = 0; ng < 2; ++ng)
          orow[ng * 32] = (__bf16)acc[mg][ng][r];
      }
    }
  }
}

// ---------------------------------------------------------------------------
// Combine, IN PLACE: block t owns y[t]'s 4 KiB = [buf0[t] | buf1[t]] bf16.
// Load both halves, barrier (drains vmcnt), overwrite with fp32 y.
// ---------------------------------------------------------------------------
__global__ __launch_bounds__(256)
void combine(const float* __restrict__ probs, float* __restrict__ y) {
  const int t = blockIdx.x;
  const int c = threadIdx.x * 4;
  const __bf16* bt = (const __bf16*)(y + (size_t)t * C_DIM);
  const bf16x4v b0 = *(const bf16x4v*)(bt + c);
  const bf16x4v b1 = *(const bf16x4v*)(bt + 1024 + c);
  const float p0 = probs[2 * t], p1 = probs[2 * t + 1];
  __syncthreads();   // all reads of this block's region complete before writes
  float4 o = { p0 * (float)b0[0] + p1 * (float)b1[0],
               p0 * (float)b0[1] + p1 * (float)b1[1],
               p0 * (float)b0[2] + p1 * (float)b1[2],
               p0 * (float)b0[3] + p1 * (float)b1[3] };
  *(float4*)(y + (size_t)t * C_DIM + c) = o;
}

extern "C" void kernel_launch(void* const* d_in, const int* in_sizes, int n_in,
                              void* d_out, int out_size, void* d_ws, size_t ws_size,
                              hipStream_t stream) {
  const float* x    = (const float*)d_in[0];
  const float* wg   = (const float*)d_in[1];
  const float* bias = (const float*)d_in[2];
  const float* wcfc = (const float*)d_in[3];

  float* y     = (float*)d_out;
  float* probs = y + (size_t)N_TOK * C_DIM;
  __bf16* buf  = (__bf16*)d_out;         // slot buffers packed in y region

  char* ws   = (char*)d_ws;
  int*    cnt  = (int*)(ws + WS_CNT);
  int*    perm = (int*)(ws + WS_PERM);
  __bf16* xb   = (__bf16*)(ws + WS_XB);
  __bf16* Wt   = (__bf16*)(ws + WS_WT);

  hipMemsetAsync(cnt, 0, N_EXP * sizeof(int), stream);

  prep_kernel<<<256 + 8192, 256, 0, stream>>>(x, wg, bias, wcfc, xb, probs,
                                              Wt, cnt, perm);
  moe_gemm<<<dim3(8, 32, 8), 256, 0, stream>>>(xb, Wt, cnt, perm, buf);
  combine<<<N_TOK, 256, 0, stream>>>(probs, y);
}

// Round 7
// 135.718 us; speedup vs baseline: 1.0331x; 1.0331x over previous
//
#include <hip/hip_runtime.h>
#include <math.h>

typedef __attribute__((ext_vector_type(8))) __bf16 bf16x8;
typedef __attribute__((ext_vector_type(4))) __bf16 bf16x4v;
typedef __attribute__((ext_vector_type(16))) float f32x16;

#define N_TOK  4096
#define C_DIM  1024
#define N_EXP  8
#define CAP    4096

// workspace layout (bytes). ws_size ~= 256 MiB (poison-fill WRITE_SIZE evidence).
// NOTE round-3 postmortem: '<<' binds looser than '+' — keep offsets parenthesized.
#define WS_CNT    0                                   // 32 B
#define WS_PERM   32768                               // 128 KB: per-expert slot lists
#define WS_XB     ((size_t)1 << 20)                   // 8 MB: x in bf16
#define WS_WT     (WS_XB + ((size_t)8 << 20))         // 16 MB: W^T bf16

// async global->LDS, 16B per lane. LDS dest is wave-uniform base + lane*16.
#define GLD16(g, l)                                                        \
  __builtin_amdgcn_global_load_lds(                                        \
      (const __attribute__((address_space(1))) void*)(g),                  \
      (__attribute__((address_space(3))) void*)(l), 16, 0, 0)

// ---------------------------------------------------------------------------
// prep: fused router (blocks 0..255) + W transpose/bf16 (blocks 256..8447).
// Router blocks also build the per-expert slot lists (LDS-aggregated counts
// -> 8 spread global atomics per block; cnt pre-zeroed by a 32 B memset).
// ---------------------------------------------------------------------------
__global__ __launch_bounds__(256)
void prep_kernel(const float* __restrict__ x, const float* __restrict__ wg,
                 const float* __restrict__ bias, const float* __restrict__ W,
                 __bf16* __restrict__ xb, float* __restrict__ probs,
                 __bf16* __restrict__ Wt, int* __restrict__ cnt,
                 int* __restrict__ perm) {
  __shared__ __align__(16) char smem[32768];
  __shared__ int lcnt[N_EXP], base[N_EXP];
  const int tid = threadIdx.x;

  if (blockIdx.x < 256) {
    // ---------------- router ----------------
    float (*wgT)[C_DIM] = (float (*)[C_DIM])smem;   // [N_EXP][C_DIM], 32 KB
    if (tid < N_EXP) lcnt[tid] = 0;

#pragma unroll
    for (int i = 0; i < 8; ++i) {
      const float4 v = ((const float4*)wg)[i * 256 + tid];
      const int f = (i * 256 + tid) * 4;
      const int c = f >> 3;
      const int e = f & 7;
      wgT[e][c] = v.x; wgT[e + 1][c] = v.y; wgT[e + 2][c] = v.z; wgT[e + 3][c] = v.w;
    }
    __syncthreads();

    const int lane = tid & 63;
    const int wv   = tid >> 6;
    int re0[4], re1[4], rs0[4], rs1[4];   // lane0-valid per s

#pragma unroll
    for (int s = 0; s < 4; ++s) {
      const int t = blockIdx.x * 16 + wv * 4 + s;
      const float4* xrow = (const float4*)(x + (size_t)t * C_DIM);
      float acc[N_EXP];
#pragma unroll
      for (int e = 0; e < N_EXP; ++e) acc[e] = 0.f;

#pragma unroll
      for (int j = 0; j < 4; ++j) {
        const int c4 = j * 64 + lane;
        const float4 v = xrow[c4];
        bf16x4v bv = { (__bf16)v.x, (__bf16)v.y, (__bf16)v.z, (__bf16)v.w };
        *(bf16x4v*)(xb + (size_t)t * C_DIM + c4 * 4) = bv;
#pragma unroll
        for (int e = 0; e < N_EXP; ++e) {
          const float4 w = *(const float4*)&wgT[e][c4 * 4];
          acc[e] += v.x * w.x + v.y * w.y + v.z * w.z + v.w * w.w;
        }
      }

#pragma unroll
      for (int off = 32; off >= 1; off >>= 1) {
#pragma unroll
        for (int e = 0; e < N_EXP; ++e) acc[e] += __shfl_xor(acc[e], off, 64);
      }

      if (lane == 0) {
        float l[N_EXP];
#pragma unroll
        for (int e = 0; e < N_EXP; ++e) l[e] = acc[e] + bias[e];
        int e0 = 0;
#pragma unroll
        for (int e = 1; e < N_EXP; ++e) if (l[e] > l[e0]) e0 = e;
        int e1 = (e0 == 0) ? 1 : 0;
#pragma unroll
        for (int e = 0; e < N_EXP; ++e) if (e != e0 && l[e] > l[e1]) e1 = e;
        const float p0 = 1.f / (1.f + expf(l[e1] - l[e0]));
        probs[t * 2]     = p0;
        probs[t * 2 + 1] = 1.f - p0;
        re0[s] = e0; re1[s] = e1;
        rs0[s] = atomicAdd(&lcnt[e0], 1);
        rs1[s] = atomicAdd(&lcnt[e1], 1);
      }
    }
    __syncthreads();
    if (tid < N_EXP) base[tid] = atomicAdd(&cnt[tid], lcnt[tid]);
    __syncthreads();
    if (lane == 0) {
#pragma unroll
      for (int s = 0; s < 4; ++s) {
        const int t = blockIdx.x * 16 + wv * 4 + s;
        perm[re0[s] * CAP + base[re0[s]] + rs0[s]] = t * 2;
        perm[re1[s] * CAP + base[re1[s]] + rs1[s]] = t * 2 + 1;
      }
    }
  } else {
    // ---------------- W transpose + bf16 convert ----------------
    __bf16 (*tile)[33] = (__bf16 (*)[33])smem;      // [32][33]
    const int b  = blockIdx.x - 256;
    const int e  = b >> 10;
    const int r  = b & 1023;
    const int i0 = (r >> 5) * 32;
    const int o0 = (r & 31) * 32;
    const float* We  = W  + (size_t)e * C_DIM * C_DIM;
    __bf16*      Wte = Wt + (size_t)e * C_DIM * C_DIM;
    const int tx = tid & 31, ty = tid >> 5;
#pragma unroll
    for (int j = 0; j < 32; j += 8)
      tile[ty + j][tx] = (__bf16)We[(size_t)(i0 + ty + j) * C_DIM + o0 + tx];
    __syncthreads();
#pragma unroll
    for (int j = 0; j < 32; j += 8)
      Wte[(size_t)(o0 + ty + j) * C_DIM + i0 + tx] = tile[tx][ty + j];
  }
}

// ---------------------------------------------------------------------------
// Grouped GEMM: 64m x 128n tile (round-7: halved m-tile -> ~1056 active
// blocks ~ 4+/CU, vs 512 = 2/CU at 128m — the gemm is latency-bound at the
// per-iter barrier drain, so active-block overlap is the lever). 4 waves,
// each 32x64 via 1x2 of 32x32x16 bf16 MFMA (layout validated round 6).
// 1D grid, expert-fastest decode (e = gid&7) as XCD-L2 locality heuristic.
// XOR chunk swizzle as before. Epilogue: bf16 stores into slot buffer packed
// in d_out's y region: token t's 4 KiB = [buf0[t] | buf1[t]].
// ---------------------------------------------------------------------------
__global__ __launch_bounds__(256)
void moe_gemm(const __bf16* __restrict__ xb, const __bf16* __restrict__ Wt,
              const int* __restrict__ cnt, const int* __restrict__ perm,
              __bf16* __restrict__ buf) {
  const int gid = blockIdx.x;
  const int e   = gid & 7;
  const int n0  = ((gid >> 3) & 7) * 128;
  const int m0  = (gid >> 6) * 64;
  const int count = cnt[e];
  if (m0 >= count) return;

  const int*    permE = perm + e * CAP;
  const __bf16* We    = Wt + (size_t)e * C_DIM * C_DIM;

  __shared__ char AsB[8192];    // 64 rows x 128 B (64 bf16), chunk-swizzled
  __shared__ char BsB[16384];   // 128 rows x 128 B

  const int tid  = threadIdx.x;
  const int lane = tid & 63;
  const int wv   = tid >> 6;
  const int wr = wv >> 1, wc = wv & 1;      // wave: rows wr*32, cols wc*64
  const int l32 = lane & 31, hi = lane >> 5;

  const int rsub  = lane >> 3;          // 0..7
  const int chunk = (lane & 7) ^ rsub;  // XOR swizzle key = row&7
  int tk[2];
#pragma unroll
  for (int q = 0; q < 2; ++q) {
    const int i = m0 + wv * 16 + q * 8 + rsub;
    tk[q] = (i < count) ? (permE[i] >> 1) : 0;
  }
  const char* gB = (const char*)We + (size_t)(n0 + wv * 32 + rsub) * 2048 + chunk * 16;
  char* ldsA = AsB + wv * 2048;     // + q*1024; lane*16 appended by HW
  char* ldsB = BsB + wv * 4096;

  f32x16 acc[2];
#pragma unroll
  for (int ng = 0; ng < 2; ++ng)
#pragma unroll
    for (int r = 0; r < 16; ++r) acc[ng][r] = 0.f;

  for (int kt = 0; kt < 16; ++kt) {
    const int kb = kt * 128;   // byte offset along K (64 bf16)
#pragma unroll
    for (int q = 0; q < 2; ++q)
      GLD16((const char*)xb + (size_t)tk[q] * 2048 + kb + chunk * 16,
            ldsA + q * 1024);
#pragma unroll
    for (int q = 0; q < 4; ++q)
      GLD16(gB + (size_t)q * 8 * 2048 + kb, ldsB + q * 1024);
    __syncthreads();

#pragma unroll
    for (int ks = 0; ks < 4; ++ks) {
      const int c = ks * 2 + hi;        // 16B chunk index along the 128B row
      const int rA = wr * 32 + l32;
      const bf16x8 af = *(const bf16x8*)(AsB + rA * 128 + ((c ^ (rA & 7)) << 4));
      bf16x8 bfr[2];
#pragma unroll
      for (int ng = 0; ng < 2; ++ng) {
        const int rB = wc * 64 + ng * 32 + l32;
        bfr[ng] = *(const bf16x8*)(BsB + rB * 128 + ((c ^ (rB & 7)) << 4));
      }
#pragma unroll
      for (int ng = 0; ng < 2; ++ng)
        acc[ng] = __builtin_amdgcn_mfma_f32_32x32x16_bf16(af, bfr[ng], acc[ng], 0, 0, 0);
    }
    __syncthreads();
  }

  // epilogue: C/D row=(reg&3)+8*(reg>>2)+4*hi, col=l32 (validated round 6)
#pragma unroll
  for (int r = 0; r < 16; ++r) {
    const int row = (r & 3) + 8 * (r >> 2) + 4 * hi;
    const int i = m0 + wr * 32 + row;
    if (i < count) {
      const int pe = permE[i];
      __bf16* orow = buf + (size_t)(pe >> 1) * 2048 + (pe & 1) * 1024 +
                     n0 + wc * 64 + l32;
      orow[0]  = (__bf16)acc[0][r];
      orow[32] = (__bf16)acc[1][r];
    }
  }
}

// ---------------------------------------------------------------------------
// Combine, IN PLACE: block t owns y[t]'s 4 KiB = [buf0[t] | buf1[t]] bf16.
// Load both halves, barrier (drains vmcnt), overwrite with fp32 y.
// ---------------------------------------------------------------------------
__global__ __launch_bounds__(256)
void combine(const float* __restrict__ probs, float* __restrict__ y) {
  const int t = blockIdx.x;
  const int c = threadIdx.x * 4;
  const __bf16* bt = (const __bf16*)(y + (size_t)t * C_DIM);
  const bf16x4v b0 = *(const bf16x4v*)(bt + c);
  const bf16x4v b1 = *(const bf16x4v*)(bt + 1024 + c);
  const float p0 = probs[2 * t], p1 = probs[2 * t + 1];
  __syncthreads();   // all reads of this block's region complete before writes
  float4 o = { p0 * (float)b0[0] + p1 * (float)b1[0],
               p0 * (float)b0[1] + p1 * (float)b1[1],
               p0 * (float)b0[2] + p1 * (float)b1[2],
               p0 * (float)b0[3] + p1 * (float)b1[3] };
  *(float4*)(y + (size_t)t * C_DIM + c) = o;
}

extern "C" void kernel_launch(void* const* d_in, const int* in_sizes, int n_in,
                              void* d_out, int out_size, void* d_ws, size_t ws_size,
                              hipStream_t stream) {
  const float* x    = (const float*)d_in[0];
  const float* wg   = (const float*)d_in[1];
  const float* bias = (const float*)d_in[2];
  const float* wcfc = (const float*)d_in[3];

  float* y     = (float*)d_out;
  float* probs = y + (size_t)N_TOK * C_DIM;
  __bf16* buf  = (__bf16*)d_out;         // slot buffers packed in y region

  char* ws   = (char*)d_ws;
  int*    cnt  = (int*)(ws + WS_CNT);
  int*    perm = (int*)(ws + WS_PERM);
  __bf16* xb   = (__bf16*)(ws + WS_XB);
  __bf16* Wt   = (__bf16*)(ws + WS_WT);

  hipMemsetAsync(cnt, 0, N_EXP * sizeof(int), stream);

  prep_kernel<<<256 + 8192, 256, 0, stream>>>(x, wg, bias, wcfc, xb, probs,
                                              Wt, cnt, perm);
  moe_gemm<<<8 * 8 * 64, 256, 0, stream>>>(xb, Wt, cnt, perm, buf);
  combine<<<N_TOK, 256, 0, stream>>>(probs, y);
}